// Round 10
// baseline (534.235 us; speedup 1.0000x reference)
//
#include <hip/hip_runtime.h>

// GNNTEP R10: R9 skeleton + coalesced epilogue stores.
// The H1T/H2T stores were 8B-per-lane row-scatters (lane -> different 1KB row)
// = 64 L2 transactions per wave store. Fix: frag->LDS repack ([f][128n]
// swizzled tile in the freed Ab buffers) then coalesced read-out (16 lanes =
// 256B contiguous dwordx4 per row). gnn1's W1 operands move LDS->global regs
// (L2-hot) to free Ab; stats atomics deferred to kernel end.

typedef short  s16x8 __attribute__((ext_vector_type(8)));
typedef float  f32x4 __attribute__((ext_vector_type(4)));

#define NN   512
#define NB   1024
#define NH   64
#define LDT  72

#define MFMA16(a, b, c) __builtin_amdgcn_mfma_f32_16x16x32_bf16((a), (b), (c), 0, 0, 0)

#define GLOAD16(g, l) __builtin_amdgcn_global_load_lds( \
    (const __attribute__((address_space(1))) unsigned*)(g), \
    (__attribute__((address_space(3))) unsigned*)(l), 16, 0, 0)

__device__ __forceinline__ unsigned short f2bf(float f) {
  union { float f; unsigned u; } v; v.f = f;
  unsigned r = v.u + 0x7fffu + ((v.u >> 16) & 1u);   // RNE
  return (unsigned short)(r >> 16);
}
__device__ __forceinline__ float bf2f(unsigned short h) {
  union { unsigned u; float f; } v; v.u = ((unsigned)h) << 16;
  return v.f;
}

// ---------------- merged prep: transpose_x (8192) + prep_adj (1024) + prep_w (48) ----------------
__global__ __launch_bounds__(256)
void k_prep(const float* __restrict__ X, const float* __restrict__ adj,
            const float* __restrict__ W1, const float* __restrict__ W2,
            unsigned short* __restrict__ Xt, unsigned short* __restrict__ adjbf,
            unsigned short* __restrict__ W1t, unsigned short* __restrict__ W2t) {
  __shared__ unsigned short T[64 * LDT];
  int blk = blockIdx.x, t = threadIdx.x;
  if (blk < 8192) {
    int b = blk >> 3, m0 = (blk & 7) << 6;
    int r = t >> 2, seg = t & 3;
    const float* src = X + ((size_t)b * NN + m0 + r) * NH + seg * 16;
#pragma unroll
    for (int e = 0; e < 16; ++e) T[(seg * 16 + e) * LDT + r] = f2bf(src[e]);
    __syncthreads();
    unsigned short* dst = Xt + ((size_t)b * NH + r) * NN + m0 + seg * 16;
    const unsigned short* sT = &T[r * LDT + seg * 16];
    *(s16x8*)dst       = *(const s16x8*)sT;
    *(s16x8*)(dst + 8) = *(const s16x8*)(sT + 8);
  } else if (blk < 9216) {
    int idx = (blk - 8192) * 256 + t;            // 512*512
    int n = idx >> 9, m = idx & 511;
    float v = adj[idx];
    if (n == m) v = 0.f;
    adjbf[idx] = f2bf(v);
  } else {
    int idx = (blk - 9216) * 256 + t;            // 3*64*64
    int i = idx >> 12, rc_ = idx & 4095;
    int src = (i << 12) + ((rc_ & 63) << 6) + (rc_ >> 6);
    W1t[idx] = f2bf(W1[src]);
    W2t[idx] = f2bf(W2[src]);
  }
}

// ---------------- k_gnn1: 2-batch AX tile + 3x h1 projections + stats1 ----------------
__global__ __launch_bounds__(512)
void k_gnn1(const unsigned short* __restrict__ Xt, const unsigned short* __restrict__ adjbf,
            const unsigned short* __restrict__ W1t, const float* __restrict__ b1,
            unsigned short* __restrict__ H1T, float* __restrict__ SS1, float* __restrict__ SQ1) {
  __shared__ unsigned short Ab[2][2][4096];    // [b][dbuf]; reused as repack tile
  __shared__ unsigned short Bb[2][8192];       // [dbuf]; reused as T0/T1
  int h = blockIdx.x;
  int blk = (h & 7) * 256 + (h >> 3);          // bijective (2048 % 8 == 0)
  int bp = blk >> 2, n0 = (blk & 3) << 7;
  int b0 = bp * 2, b1v = bp * 2 + 1;
  int t = threadIdx.x, lane = t & 63, wid = t >> 6;
  int wf = wid & 1, wn = wid >> 1;
  int arow = wid * 8 + (lane >> 3);            // 0..63 (= w)
  int swz = ((lane & 7) ^ (arow & 7)) << 3;
  const unsigned short* aS0 = Xt + ((size_t)b0  * NH + arow) * NN + swz;
  const unsigned short* aS1 = Xt + ((size_t)b1v * NH + arow) * NN + swz;
  const unsigned short* bS0 = adjbf + (size_t)(n0 + arow) * NN + swz;
  const unsigned short* bS1 = adjbf + (size_t)(n0 + 64 + arow) * NN + swz;

  GLOAD16(aS0, &Ab[0][0][wid * 512]);
  GLOAD16(aS1, &Ab[1][0][wid * 512]);
  GLOAD16(bS0, &Bb[0][wid * 512]);
  GLOAD16(bS1, &Bb[0][4096 + wid * 512]);
  __syncthreads();

  f32x4 acc[2][2][2] = {};
  for (int kt = 0; kt < 8; ++kt) {
    int cur = kt & 1;
    if (kt < 7) {
      int off = (kt + 1) * 64;
      GLOAD16(aS0 + off, &Ab[0][cur ^ 1][wid * 512]);
      GLOAD16(aS1 + off, &Ab[1][cur ^ 1][wid * 512]);
      GLOAD16(bS0 + off, &Bb[cur ^ 1][wid * 512]);
      GLOAD16(bS1 + off, &Bb[cur ^ 1][4096 + wid * 512]);
    }
    const unsigned short* B = Bb[cur];
#pragma unroll
    for (int kk = 0; kk < 2; ++kk) {
      int ks = (lane >> 4) + kk * 4;                       // k-slot 0..7
      int ra0 = wf * 32 + (lane & 15), ra1 = ra0 + 16;
      int rb0 = wn * 32 + (lane & 15), rb1 = rb0 + 16;
      s16x8 bf0 = *(const s16x8*)&B[rb0 * 64 + ((ks ^ (rb0 & 7)) << 3)];
      s16x8 bf1 = *(const s16x8*)&B[rb1 * 64 + ((ks ^ (rb1 & 7)) << 3)];
#pragma unroll
      for (int bs = 0; bs < 2; ++bs) {
        const unsigned short* A = Ab[bs][cur];
        s16x8 a0 = *(const s16x8*)&A[ra0 * 64 + ((ks ^ (ra0 & 7)) << 3)];
        s16x8 a1 = *(const s16x8*)&A[ra1 * 64 + ((ks ^ (ra1 & 7)) << 3)];
        acc[bs][0][0] = MFMA16(a0, bf0, acc[bs][0][0]);
        acc[bs][1][0] = MFMA16(a1, bf0, acc[bs][1][0]);
        acc[bs][0][1] = MFMA16(a0, bf1, acc[bs][0][1]);
        acc[bs][1][1] = MFMA16(a1, bf1, acc[bs][1][1]);
      }
    }
    __syncthreads();
  }
  // T_b[n 128][w 64] (swizzled): T0 = Bb[0], T1 = Bb[1]
#pragma unroll
  for (int bs = 0; bs < 2; ++bs) {
    unsigned short* T = Bb[bs];
#pragma unroll
    for (int fi = 0; fi < 2; ++fi)
#pragma unroll
      for (int fj = 0; fj < 2; ++fj) {
        int nl = wn * 32 + fj * 16 + (lane & 15);
        int w0 = wf * 32 + fi * 16 + (lane >> 4) * 4;
        ushort4 p;
        p.x = f2bf(acc[bs][fi][fj][0]); p.y = f2bf(acc[bs][fi][fj][1]);
        p.z = f2bf(acc[bs][fi][fj][2]); p.w = f2bf(acc[bs][fi][fj][3]);
        *(ushort4*)&T[nl * 64 + (((w0 >> 3) ^ (nl & 7)) << 3) + (w0 & 7)] = p;
      }
  }
  __syncthreads();
  // h1 phase: D2[n][f] = T_b @ W1t[i]; W1 frags direct from global (L2-hot)
  int nrow = wid * 16 + (lane & 15);
  int nbase = wid * 16 + (lane >> 4) * 4;
  s16x8 aT[2][2];
#pragma unroll
  for (int bs = 0; bs < 2; ++bs)
#pragma unroll
    for (int kk = 0; kk < 2; ++kk) {
      int ks = (lane >> 4) + kk * 4;
      aT[bs][kk] = *(const s16x8*)&Bb[bs][nrow * 64 + ((ks ^ (nrow & 7)) << 3)];
    }
  unsigned short* Rep = &Ab[0][0][0];          // 32KB repack tile [2bs][64f][128n]
  float sA[3][4], qA[3][4];
#pragma unroll
  for (int i = 0; i < 3; ++i) {
    s16x8 bw[2][4];
#pragma unroll
    for (int kk = 0; kk < 2; ++kk)
#pragma unroll
      for (int fd = 0; fd < 4; ++fd)
        bw[kk][fd] = *(const s16x8*)&W1t[i * 4096 + (fd * 16 + (lane & 15)) * 64
                                         + kk * 32 + (lane >> 4) * 8];
    f32x4 acc2[2][4] = {};
#pragma unroll
    for (int bs = 0; bs < 2; ++bs)
#pragma unroll
      for (int kk = 0; kk < 2; ++kk) {
        acc2[bs][0] = MFMA16(aT[bs][kk], bw[kk][0], acc2[bs][0]);
        acc2[bs][1] = MFMA16(aT[bs][kk], bw[kk][1], acc2[bs][1]);
        acc2[bs][2] = MFMA16(aT[bs][kk], bw[kk][2], acc2[bs][2]);
        acc2[bs][3] = MFMA16(aT[bs][kk], bw[kk][3], acc2[bs][3]);
      }
    __syncthreads();   // read-out of i-1 done before Rep overwrite
    float svr[4] = {0.f, 0.f, 0.f, 0.f}, sqr[4] = {0.f, 0.f, 0.f, 0.f};
#pragma unroll
    for (int bs = 0; bs < 2; ++bs)
#pragma unroll
      for (int fd = 0; fd < 4; ++fd) {
        int f = fd * 16 + (lane & 15);
        float bia = b1[i * 64 + f];
        float x0 = fmaxf(acc2[bs][fd][0] + bia, 0.f);
        float x1 = fmaxf(acc2[bs][fd][1] + bia, 0.f);
        float x2 = fmaxf(acc2[bs][fd][2] + bia, 0.f);
        float x3 = fmaxf(acc2[bs][fd][3] + bia, 0.f);
        svr[0] += x0; svr[1] += x1; svr[2] += x2; svr[3] += x3;
        sqr[0] += x0 * x0; sqr[1] += x1 * x1; sqr[2] += x2 * x2; sqr[3] += x3 * x3;
        ushort4 p;
        p.x = f2bf(x0); p.y = f2bf(x1); p.z = f2bf(x2); p.w = f2bf(x3);
        *(ushort4*)&Rep[bs * 8192 + f * 128 + (((nbase >> 3) ^ (f & 7)) << 3) + (nbase & 7)] = p;
      }
#pragma unroll
    for (int rr = 0; rr < 4; ++rr) {
      float sv = svr[rr], qv = sqr[rr];
      sv += __shfl_xor(sv, 1); sv += __shfl_xor(sv, 2); sv += __shfl_xor(sv, 4); sv += __shfl_xor(sv, 8);
      qv += __shfl_xor(qv, 1); qv += __shfl_xor(qv, 2); qv += __shfl_xor(qv, 4); qv += __shfl_xor(qv, 8);
      sA[i][rr] = sv; qA[i][rr] = qv;
    }
    __syncthreads();   // Rep complete
    unsigned short* H1i = H1T + (size_t)i * 33554432u;
#pragma unroll
    for (int bs = 0; bs < 2; ++bs) {
      int bcur = bs ? b1v : b0;
#pragma unroll
      for (int half = 0; half < 2; ++half) {
        int f = (t >> 4) + half * 32;
        int c = t & 15;
        s16x8 v = *(const s16x8*)&Rep[bs * 8192 + f * 128 + ((c ^ (f & 7)) << 3)];
        *(s16x8*)&H1i[((size_t)bcur * NH + f) * NN + n0 + c * 8] = v;
      }
    }
  }
  // deferred fire-and-forget stats atomics
  if ((lane & 15) == 0) {
#pragma unroll
    for (int i = 0; i < 3; ++i)
#pragma unroll
      for (int rr = 0; rr < 4; ++rr) {
        int n = n0 + wid * 16 + (lane >> 4) * 4 + rr;
        atomicAdd(&SS1[i * 512 + n], sA[i][rr]);
        atomicAdd(&SQ1[i * 512 + n], qA[i][rr]);
      }
  }
}

// ---------------- adjB_all: all 3 iterations; BN1 finalize inline ----------------
__global__ __launch_bounds__(256)
void k_adjb_all(const unsigned short* __restrict__ adjbf,
                const float* __restrict__ SS1, const float* __restrict__ SQ1,
                const float* __restrict__ g1, const float* __restrict__ be1,
                unsigned short* __restrict__ ADJB3, float* __restrict__ RC3,
                float* __restrict__ A1, float* __restrict__ C1) {
  __shared__ float red[256];
  int blk = blockIdx.x;                        // 1536 = 3*512
  int i = blk >> 9, n = blk & 511, t = threadIdx.x;
  const float* Ssum = SS1 + i * 512;
  const float* Ssq  = SQ1 + i * 512;
  const float* g    = g1 + i * 512;
  const float* be   = be1 + i * 512;
  unsigned short* adjB = ADJB3 + (size_t)i * 262144;
  float acc = 0.f;
#pragma unroll
  for (int hh = 0; hh < 2; ++hh) {
    int m = t + hh * 256;
    float mean = Ssum[m] * (1.f / 65536.f);
    float var  = Ssq[m] * (1.f / 65536.f) - mean * mean;
    float a = g[m] * rsqrtf(var + 1e-5f);
    float c = be[m] - mean * a;
    if (n == 0) { A1[i * 512 + m] = a; C1[i * 512 + m] = c; }
    float av = bf2f(adjbf[n * NN + m]);
    adjB[n * NN + m] = f2bf(av * a);
    acc += av * c;
  }
  red[t] = acc; __syncthreads();
  for (int s = 128; s > 0; s >>= 1) { if (t < s) red[t] += red[t + s]; __syncthreads(); }
  if (t == 0) RC3[i * 512 + n] = red[0];
}

// ---------------- min over n of a2[n]*h2+c2[n] (+skip), BN2 finalize inline ----------------
__global__ __launch_bounds__(256)
void k_minrow_out(const unsigned short* __restrict__ Ht,
                  const float* __restrict__ Ssum, const float* __restrict__ Ssq,
                  const float* __restrict__ g, const float* __restrict__ be,
                  const float* __restrict__ skip_i, float* __restrict__ outs, int i) {
  int t = threadIdx.x, lane = t & 63, wid = t >> 6;
  int row = blockIdx.x * 4 + wid;          // b*64 + d
  int b = row >> 6, d = row & 63;
  s16x8 hv = *(const s16x8*)(Ht + (size_t)row * NN + lane * 8);
  float m = 1e30f;
#pragma unroll
  for (int e = 0; e < 8; ++e) {
    int mm = lane * 8 + e;
    float mean = Ssum[mm] * (1.f / 65536.f);
    float var  = Ssq[mm] * (1.f / 65536.f) - mean * mean;
    float a = g[mm] * rsqrtf(var + 1e-5f);
    float c = be[mm] - mean * a;
    m = fminf(m, a * bf2f((unsigned short)hv[e]) + c);
  }
#pragma unroll
  for (int off = 1; off < 64; off <<= 1) m = fminf(m, __shfl_xor(m, off));
  if (lane == 0) outs[(size_t)b * 192 + i * 64 + d] = m + skip_i[row];
}

// ---------------- layer2: 2-batch, fused stage2 + skip-min + stats2 ----------------
__global__ __launch_bounds__(512)
void k_layer2(const unsigned short* __restrict__ H1t_i, const unsigned short* __restrict__ adjB,
              const float* __restrict__ rc, const unsigned short* __restrict__ W2t_i,
              const float* __restrict__ b2_i, unsigned short* __restrict__ H2t,
              float* __restrict__ Ssum2, float* __restrict__ Ssq2,
              const float* __restrict__ A1v, const float* __restrict__ C1v,
              float* __restrict__ skip_i) {
  __shared__ unsigned short Ab[2][2][4096];    // [b][dbuf]; reused as repack tile
  __shared__ unsigned short Bb[2][8192];       // reused as Gt0/Gt1
  __shared__ float acs[512], ccs[512];
  int h = blockIdx.x;
  int blk = (h & 7) * 256 + (h >> 3);
  int bp = blk >> 2, n0 = (blk & 3) << 7;
  int b0 = bp * 2, b1v = bp * 2 + 1;
  int t = threadIdx.x, lane = t & 63, wid = t >> 6;
  int wf = wid & 1, wn = wid >> 1;
  bool do_min = (n0 == 0);
  int arow = wid * 8 + (lane >> 3);            // 0..63 (= f)
  int swz = ((lane & 7) ^ (arow & 7)) << 3;
  const unsigned short* aS0 = H1t_i + ((size_t)b0  * NH + arow) * NN + swz;
  const unsigned short* aS1 = H1t_i + ((size_t)b1v * NH + arow) * NN + swz;
  const unsigned short* bS0 = adjB + (size_t)(n0 + arow) * NN + swz;
  const unsigned short* bS1 = adjB + (size_t)(n0 + 64 + arow) * NN + swz;
  acs[t] = A1v[t]; ccs[t] = C1v[t];
  float rcv[2];
  rcv[0] = rc[n0 + wn * 32 + (lane & 15)];
  rcv[1] = rc[n0 + wn * 32 + 16 + (lane & 15)];

  GLOAD16(aS0, &Ab[0][0][wid * 512]);
  GLOAD16(aS1, &Ab[1][0][wid * 512]);
  GLOAD16(bS0, &Bb[0][wid * 512]);
  GLOAD16(bS1, &Bb[0][4096 + wid * 512]);
  __syncthreads();

  float mn0 = 1e30f, mn1 = 1e30f;
  f32x4 acc[2][2][2] = {};
  for (int kt = 0; kt < 8; ++kt) {
    int cur = kt & 1;
    if (kt < 7) {
      int off = (kt + 1) * 64;
      GLOAD16(aS0 + off, &Ab[0][cur ^ 1][wid * 512]);
      GLOAD16(aS1 + off, &Ab[1][cur ^ 1][wid * 512]);
      GLOAD16(bS0 + off, &Bb[cur ^ 1][wid * 512]);
      GLOAD16(bS1 + off, &Bb[cur ^ 1][4096 + wid * 512]);
    }
    if (do_min) {
      int s2 = ((lane & 7) ^ (arow & 7)) << 3;
      s16x8 av0 = *(const s16x8*)&Ab[0][cur][arow * 64 + s2];
      s16x8 av1 = *(const s16x8*)&Ab[1][cur][arow * 64 + s2];
      int m0 = kt * 64 + ((lane & 7) << 3);
#pragma unroll
      for (int e = 0; e < 8; ++e) {
        mn0 = fminf(mn0, acs[m0 + e] * bf2f((unsigned short)av0[e]) + ccs[m0 + e]);
        mn1 = fminf(mn1, acs[m0 + e] * bf2f((unsigned short)av1[e]) + ccs[m0 + e]);
      }
    }
    const unsigned short* B = Bb[cur];
#pragma unroll
    for (int kk = 0; kk < 2; ++kk) {
      int ks = (lane >> 4) + kk * 4;
      int ra0 = wf * 32 + (lane & 15), ra1 = ra0 + 16;
      int rb0 = wn * 32 + (lane & 15), rb1 = rb0 + 16;
      s16x8 bf0 = *(const s16x8*)&B[rb0 * 64 + ((ks ^ (rb0 & 7)) << 3)];
      s16x8 bf1 = *(const s16x8*)&B[rb1 * 64 + ((ks ^ (rb1 & 7)) << 3)];
#pragma unroll
      for (int bs = 0; bs < 2; ++bs) {
        const unsigned short* A = Ab[bs][cur];
        s16x8 a0 = *(const s16x8*)&A[ra0 * 64 + ((ks ^ (ra0 & 7)) << 3)];
        s16x8 a1 = *(const s16x8*)&A[ra1 * 64 + ((ks ^ (ra1 & 7)) << 3)];
        acc[bs][0][0] = MFMA16(a0, bf0, acc[bs][0][0]);
        acc[bs][1][0] = MFMA16(a1, bf0, acc[bs][1][0]);
        acc[bs][0][1] = MFMA16(a0, bf1, acc[bs][0][1]);
        acc[bs][1][1] = MFMA16(a1, bf1, acc[bs][1][1]);
      }
    }
    __syncthreads();
  }
  if (do_min) {
    mn0 = fminf(mn0, __shfl_xor(mn0, 1)); mn1 = fminf(mn1, __shfl_xor(mn1, 1));
    mn0 = fminf(mn0, __shfl_xor(mn0, 2)); mn1 = fminf(mn1, __shfl_xor(mn1, 2));
    mn0 = fminf(mn0, __shfl_xor(mn0, 4)); mn1 = fminf(mn1, __shfl_xor(mn1, 4));
    if ((lane & 7) == 0) {
      skip_i[b0 * 64 + arow] = mn0;
      skip_i[b1v * 64 + arow] = mn1;
    }
  }
  // Gt_b[n][f] = D1[f][n] + rc[n]
#pragma unroll
  for (int bs = 0; bs < 2; ++bs) {
    unsigned short* Gt = Bb[bs];
#pragma unroll
    for (int fi = 0; fi < 2; ++fi)
#pragma unroll
      for (int fj = 0; fj < 2; ++fj) {
        int n  = wn * 32 + fj * 16 + (lane & 15);
        int f0 = wf * 32 + fi * 16 + (lane >> 4) * 4;
        ushort4 p;
        p.x = f2bf(acc[bs][fi][fj][0] + rcv[fj]); p.y = f2bf(acc[bs][fi][fj][1] + rcv[fj]);
        p.z = f2bf(acc[bs][fi][fj][2] + rcv[fj]); p.w = f2bf(acc[bs][fi][fj][3] + rcv[fj]);
        *(ushort4*)&Gt[n * 64 + (((f0 >> 3) ^ (n & 7)) << 3) + (f0 & 7)] = p;
      }
  }
  __syncthreads();
  // stage2: D2[n][d] = Gt_b @ W2t (W2 frags shared across b)
  s16x8 w2f[2][4];
  float bb[4];
#pragma unroll
  for (int kk = 0; kk < 2; ++kk)
#pragma unroll
    for (int fd = 0; fd < 4; ++fd)
      w2f[kk][fd] = *(const s16x8*)&W2t_i[(fd * 16 + (lane & 15)) * 64 + kk * 32 + (lane >> 4) * 8];
#pragma unroll
  for (int fd = 0; fd < 4; ++fd) bb[fd] = b2_i[fd * 16 + (lane & 15)];

  int nrow = wid * 16 + (lane & 15);
  int nbase = wid * 16 + (lane >> 4) * 4;
  f32x4 acc2[2][4] = {};
#pragma unroll
  for (int bs = 0; bs < 2; ++bs)
#pragma unroll
    for (int kk = 0; kk < 2; ++kk) {
      int ks = (lane >> 4) + kk * 4;
      s16x8 a = *(const s16x8*)&Bb[bs][nrow * 64 + ((ks ^ (nrow & 7)) << 3)];
      acc2[bs][0] = MFMA16(a, w2f[kk][0], acc2[bs][0]);
      acc2[bs][1] = MFMA16(a, w2f[kk][1], acc2[bs][1]);
      acc2[bs][2] = MFMA16(a, w2f[kk][2], acc2[bs][2]);
      acc2[bs][3] = MFMA16(a, w2f[kk][3], acc2[bs][3]);
    }
  // relu + stats + frag-write into repack tile [2bs][64d][128n] (Ab, free now)
  unsigned short* Rep = &Ab[0][0][0];
  float svr[4] = {0.f, 0.f, 0.f, 0.f}, sqr[4] = {0.f, 0.f, 0.f, 0.f};
#pragma unroll
  for (int bs = 0; bs < 2; ++bs)
#pragma unroll
    for (int fd = 0; fd < 4; ++fd) {
      int d = fd * 16 + (lane & 15);
      float x0 = fmaxf(acc2[bs][fd][0] + bb[fd], 0.f);
      float x1 = fmaxf(acc2[bs][fd][1] + bb[fd], 0.f);
      float x2 = fmaxf(acc2[bs][fd][2] + bb[fd], 0.f);
      float x3 = fmaxf(acc2[bs][fd][3] + bb[fd], 0.f);
      svr[0] += x0; svr[1] += x1; svr[2] += x2; svr[3] += x3;
      sqr[0] += x0 * x0; sqr[1] += x1 * x1; sqr[2] += x2 * x2; sqr[3] += x3 * x3;
      ushort4 p;
      p.x = f2bf(x0); p.y = f2bf(x1); p.z = f2bf(x2); p.w = f2bf(x3);
      *(ushort4*)&Rep[bs * 8192 + d * 128 + (((nbase >> 3) ^ (d & 7)) << 3) + (nbase & 7)] = p;
    }
  __syncthreads();
  // coalesced write-out: 16 lanes = 256B contiguous per d-row
#pragma unroll
  for (int bs = 0; bs < 2; ++bs) {
    int bcur = bs ? b1v : b0;
#pragma unroll
    for (int half = 0; half < 2; ++half) {
      int d = (t >> 4) + half * 32;
      int c = t & 15;
      s16x8 v = *(const s16x8*)&Rep[bs * 8192 + d * 128 + ((c ^ (d & 7)) << 3)];
      *(s16x8*)&H2t[((size_t)bcur * NH + d) * NN + n0 + c * 8] = v;
    }
  }
  // stats2 atomics (fire-and-forget, kernel end)
#pragma unroll
  for (int rr = 0; rr < 4; ++rr) {
    float sv = svr[rr], qv = sqr[rr];
    sv += __shfl_xor(sv, 1); sv += __shfl_xor(sv, 2); sv += __shfl_xor(sv, 4); sv += __shfl_xor(sv, 8);
    qv += __shfl_xor(qv, 1); qv += __shfl_xor(qv, 2); qv += __shfl_xor(qv, 4); qv += __shfl_xor(qv, 8);
    if ((lane & 15) == 0) {
      int n = n0 + nbase + rr;
      atomicAdd(&Ssum2[n], sv);
      atomicAdd(&Ssq2[n], qv);
    }
  }
}

// ---------------- final FC ----------------
__global__ __launch_bounds__(256)
void k_fc(const float* __restrict__ outs, const float* __restrict__ Wfc,
          const float* __restrict__ bfc, float* __restrict__ out) {
  int t = threadIdx.x;
  int b = blockIdx.x * 8 + (t >> 5), o = t & 31;
  float acc = bfc[o];
  const float* orow = outs + (size_t)b * 192;
  for (int j = 0; j < 192; ++j) acc += orow[j] * Wfc[j * 32 + o];
  out[b * 32 + o] = acc;
}

extern "C" void kernel_launch(void* const* d_in, const int* in_sizes, int n_in,
                              void* d_out, int out_size, void* d_ws, size_t ws_size,
                              hipStream_t stream) {
  const float* X   = (const float*)d_in[0];
  const float* adj = (const float*)d_in[1];
  const float* W1  = (const float*)d_in[2];
  const float* b1  = (const float*)d_in[3];
  const float* g1  = (const float*)d_in[4];
  const float* be1 = (const float*)d_in[5];
  const float* W2  = (const float*)d_in[6];
  const float* b2  = (const float*)d_in[7];
  const float* g2  = (const float*)d_in[8];
  const float* be2 = (const float*)d_in[9];
  const float* Wfc = (const float*)d_in[10];
  const float* bfc = (const float*)d_in[11];
  float* out = (float*)d_out;

  char* ws = (char*)d_ws;
  size_t off = 0;
  auto alloc = [&](size_t bytes) {
    char* p = ws + off; off += (bytes + 255) & ~(size_t)255; return p;
  };
  unsigned short* ADJBF = (unsigned short*)alloc(512 * 512 * 2);
  unsigned short* ADJB3 = (unsigned short*)alloc((size_t)3 * 512 * 512 * 2);
  unsigned short* W1T   = (unsigned short*)alloc(3 * 4096 * 2);
  unsigned short* W2T   = (unsigned short*)alloc(3 * 4096 * 2);
  float* SS1 = (float*)alloc(3 * 512 * 4);   // contiguous 4x6144B for one memset
  float* SQ1 = (float*)alloc(3 * 512 * 4);
  float* SS2 = (float*)alloc(3 * 512 * 4);
  float* SQ2 = (float*)alloc(3 * 512 * 4);
  float* A1  = (float*)alloc(3 * 512 * 4);
  float* C1  = (float*)alloc(3 * 512 * 4);
  float* RC3 = (float*)alloc(3 * 512 * 4);
  float* SKIP = (float*)alloc(3 * 1024 * 64 * 4);
  float* OUTS = (float*)alloc(1024 * 192 * 4);
  unsigned short* XT  = (unsigned short*)alloc((size_t)1024 * 64 * 512 * 2);  // reused as H2T
  unsigned short* H1T = (unsigned short*)alloc((size_t)3 * 1024 * 64 * 512 * 2);
  unsigned short* H2T = XT;   // Xt dead after k_gnn1

  hipMemsetAsync(SS1, 0, 4 * 3 * 512 * 4, stream);

  k_prep<<<9264, 256, 0, stream>>>(X, adj, W1, W2, XT, ADJBF, W1T, W2T);
  k_gnn1<<<2048, 512, 0, stream>>>(XT, ADJBF, W1T, b1, H1T, SS1, SQ1);
  k_adjb_all<<<1536, 256, 0, stream>>>(ADJBF, SS1, SQ1, g1, be1, ADJB3, RC3, A1, C1);

  for (int i = 0; i < 3; ++i) {
    k_layer2<<<2048, 512, 0, stream>>>(H1T + (size_t)i * 33554432u,
                                       ADJB3 + (size_t)i * 262144, RC3 + i * 512,
                                       W2T + i * 4096, b2 + i * 64, H2T,
                                       SS2 + i * 512, SQ2 + i * 512,
                                       A1 + i * 512, C1 + i * 512, SKIP + i * 65536);
    k_minrow_out<<<16384, 256, 0, stream>>>(H2T, SS2 + i * 512, SQ2 + i * 512,
                                            g2 + i * 512, be2 + i * 512,
                                            SKIP + i * 65536, OUTS, i);
  }
  k_fc<<<128, 256, 0, stream>>>(OUTS, Wfc, bfc, out);
}

// Round 11
// 484.983 us; speedup vs baseline: 1.1016x; 1.1016x over previous
//
#include <hip/hip_runtime.h>

// GNNTEP R11: R9 kernels exactly (R10's LDS-repack epilogues reverted: they
// added barriers+bank-conflicts and the store scatter wasn't costing HBM
// bytes). Change: the 3 independent layer2 launches merged into ONE (grid
// 6144, i from blockIdx, 3 H2T buffers), and the 3 minrow_out launches merged
// into ONE (grid 49152). Iteration tails overlap. 11 -> 7 launches.

typedef short  s16x8 __attribute__((ext_vector_type(8)));
typedef float  f32x4 __attribute__((ext_vector_type(4)));

#define NN   512
#define NB   1024
#define NH   64
#define LDT  72

#define MFMA16(a, b, c) __builtin_amdgcn_mfma_f32_16x16x32_bf16((a), (b), (c), 0, 0, 0)

#define GLOAD16(g, l) __builtin_amdgcn_global_load_lds( \
    (const __attribute__((address_space(1))) unsigned*)(g), \
    (__attribute__((address_space(3))) unsigned*)(l), 16, 0, 0)

__device__ __forceinline__ unsigned short f2bf(float f) {
  union { float f; unsigned u; } v; v.f = f;
  unsigned r = v.u + 0x7fffu + ((v.u >> 16) & 1u);   // RNE
  return (unsigned short)(r >> 16);
}
__device__ __forceinline__ float bf2f(unsigned short h) {
  union { unsigned u; float f; } v; v.u = ((unsigned)h) << 16;
  return v.f;
}

// ---------------- merged prep: transpose_x (8192) + prep_adj (1024) + prep_w (48) ----------------
__global__ __launch_bounds__(256)
void k_prep(const float* __restrict__ X, const float* __restrict__ adj,
            const float* __restrict__ W1, const float* __restrict__ W2,
            unsigned short* __restrict__ Xt, unsigned short* __restrict__ adjbf,
            unsigned short* __restrict__ W1t, unsigned short* __restrict__ W2t) {
  __shared__ unsigned short T[64 * LDT];
  int blk = blockIdx.x, t = threadIdx.x;
  if (blk < 8192) {
    int b = blk >> 3, m0 = (blk & 7) << 6;
    int r = t >> 2, seg = t & 3;
    const float* src = X + ((size_t)b * NN + m0 + r) * NH + seg * 16;
#pragma unroll
    for (int e = 0; e < 16; ++e) T[(seg * 16 + e) * LDT + r] = f2bf(src[e]);
    __syncthreads();
    unsigned short* dst = Xt + ((size_t)b * NH + r) * NN + m0 + seg * 16;
    const unsigned short* sT = &T[r * LDT + seg * 16];
    *(s16x8*)dst       = *(const s16x8*)sT;
    *(s16x8*)(dst + 8) = *(const s16x8*)(sT + 8);
  } else if (blk < 9216) {
    int idx = (blk - 8192) * 256 + t;            // 512*512
    int n = idx >> 9, m = idx & 511;
    float v = adj[idx];
    if (n == m) v = 0.f;
    adjbf[idx] = f2bf(v);
  } else {
    int idx = (blk - 9216) * 256 + t;            // 3*64*64
    int i = idx >> 12, rc_ = idx & 4095;
    int src = (i << 12) + ((rc_ & 63) << 6) + (rc_ >> 6);
    W1t[idx] = f2bf(W1[src]);
    W2t[idx] = f2bf(W2[src]);
  }
}

// ---------------- k_gnn1: 2-batch AX tile + 3x h1 projections + stats1 ----------------
__global__ __launch_bounds__(512)
void k_gnn1(const unsigned short* __restrict__ Xt, const unsigned short* __restrict__ adjbf,
            const unsigned short* __restrict__ W1t, const float* __restrict__ b1,
            unsigned short* __restrict__ H1T, float* __restrict__ SS1, float* __restrict__ SQ1) {
  __shared__ unsigned short Ab[2][2][4096];    // [b][dbuf]
  __shared__ unsigned short Bb[2][8192];       // [dbuf]; reused as T0/T1
  int h = blockIdx.x;
  int blk = (h & 7) * 256 + (h >> 3);          // bijective (2048 % 8 == 0)
  int bp = blk >> 2, n0 = (blk & 3) << 7;
  int b0 = bp * 2, b1v = bp * 2 + 1;
  int t = threadIdx.x, lane = t & 63, wid = t >> 6;
  int wf = wid & 1, wn = wid >> 1;
  int arow = wid * 8 + (lane >> 3);            // 0..63 (= w)
  int swz = ((lane & 7) ^ (arow & 7)) << 3;
  const unsigned short* aS0 = Xt + ((size_t)b0  * NH + arow) * NN + swz;
  const unsigned short* aS1 = Xt + ((size_t)b1v * NH + arow) * NN + swz;
  const unsigned short* bS0 = adjbf + (size_t)(n0 + arow) * NN + swz;
  const unsigned short* bS1 = adjbf + (size_t)(n0 + 64 + arow) * NN + swz;

  GLOAD16(aS0, &Ab[0][0][wid * 512]);
  GLOAD16(aS1, &Ab[1][0][wid * 512]);
  GLOAD16(bS0, &Bb[0][wid * 512]);
  GLOAD16(bS1, &Bb[0][4096 + wid * 512]);
  __syncthreads();

  f32x4 acc[2][2][2] = {};
  for (int kt = 0; kt < 8; ++kt) {
    int cur = kt & 1;
    if (kt < 7) {
      int off = (kt + 1) * 64;
      GLOAD16(aS0 + off, &Ab[0][cur ^ 1][wid * 512]);
      GLOAD16(aS1 + off, &Ab[1][cur ^ 1][wid * 512]);
      GLOAD16(bS0 + off, &Bb[cur ^ 1][wid * 512]);
      GLOAD16(bS1 + off, &Bb[cur ^ 1][4096 + wid * 512]);
    }
    const unsigned short* B = Bb[cur];
#pragma unroll
    for (int kk = 0; kk < 2; ++kk) {
      int ks = (lane >> 4) + kk * 4;                       // k-slot 0..7
      int ra0 = wf * 32 + (lane & 15), ra1 = ra0 + 16;
      int rb0 = wn * 32 + (lane & 15), rb1 = rb0 + 16;
      s16x8 bf0 = *(const s16x8*)&B[rb0 * 64 + ((ks ^ (rb0 & 7)) << 3)];
      s16x8 bf1 = *(const s16x8*)&B[rb1 * 64 + ((ks ^ (rb1 & 7)) << 3)];
#pragma unroll
      for (int bs = 0; bs < 2; ++bs) {
        const unsigned short* A = Ab[bs][cur];
        s16x8 a0 = *(const s16x8*)&A[ra0 * 64 + ((ks ^ (ra0 & 7)) << 3)];
        s16x8 a1 = *(const s16x8*)&A[ra1 * 64 + ((ks ^ (ra1 & 7)) << 3)];
        acc[bs][0][0] = MFMA16(a0, bf0, acc[bs][0][0]);
        acc[bs][1][0] = MFMA16(a1, bf0, acc[bs][1][0]);
        acc[bs][0][1] = MFMA16(a0, bf1, acc[bs][0][1]);
        acc[bs][1][1] = MFMA16(a1, bf1, acc[bs][1][1]);
      }
    }
    __syncthreads();
  }
  // T_b[n 128][w 64] (swizzled): T0 = Bb[0], T1 = Bb[1]
#pragma unroll
  for (int bs = 0; bs < 2; ++bs) {
    unsigned short* T = Bb[bs];
#pragma unroll
    for (int fi = 0; fi < 2; ++fi)
#pragma unroll
      for (int fj = 0; fj < 2; ++fj) {
        int nl = wn * 32 + fj * 16 + (lane & 15);
        int w0 = wf * 32 + fi * 16 + (lane >> 4) * 4;
        ushort4 p;
        p.x = f2bf(acc[bs][fi][fj][0]); p.y = f2bf(acc[bs][fi][fj][1]);
        p.z = f2bf(acc[bs][fi][fj][2]); p.w = f2bf(acc[bs][fi][fj][3]);
        *(ushort4*)&T[nl * 64 + (((w0 >> 3) ^ (nl & 7)) << 3) + (w0 & 7)] = p;
      }
  }
  // stage 3x W1 into Ab[0][0], Ab[0][1], Ab[1][0]
#pragma unroll
  for (int j = 0; j < 3; ++j) {
    unsigned short* dstp = (j == 0) ? &Ab[0][0][wid * 512]
                         : (j == 1) ? &Ab[0][1][wid * 512] : &Ab[1][0][wid * 512];
    const unsigned short* gsrc = W1t + j * 4096 + (wid * 8 + (lane >> 3)) * 64
                               + (((lane & 7) ^ (lane >> 3)) << 3);
    GLOAD16(gsrc, dstp);
  }
  __syncthreads();
  // h1 phase: D2[n][f] = T_b @ W1t[i]
  int nrow = wid * 16 + (lane & 15);
  s16x8 aT[2][2];
#pragma unroll
  for (int bs = 0; bs < 2; ++bs)
#pragma unroll
    for (int kk = 0; kk < 2; ++kk) {
      int ks = (lane >> 4) + kk * 4;
      aT[bs][kk] = *(const s16x8*)&Bb[bs][nrow * 64 + ((ks ^ (nrow & 7)) << 3)];
    }
#pragma unroll
  for (int i = 0; i < 3; ++i) {
    const unsigned short* w1p = (i == 0) ? Ab[0][0] : (i == 1) ? Ab[0][1] : Ab[1][0];
    s16x8 bw[2][4];
#pragma unroll
    for (int kk = 0; kk < 2; ++kk) {
      int ks = (lane >> 4) + kk * 4;
#pragma unroll
      for (int fd = 0; fd < 4; ++fd) {
        int fr = fd * 16 + (lane & 15);
        bw[kk][fd] = *(const s16x8*)&w1p[fr * 64 + ((ks ^ (fr & 7)) << 3)];
      }
    }
    f32x4 acc2[2][4] = {};
#pragma unroll
    for (int bs = 0; bs < 2; ++bs)
#pragma unroll
      for (int kk = 0; kk < 2; ++kk) {
        acc2[bs][0] = MFMA16(aT[bs][kk], bw[kk][0], acc2[bs][0]);
        acc2[bs][1] = MFMA16(aT[bs][kk], bw[kk][1], acc2[bs][1]);
        acc2[bs][2] = MFMA16(aT[bs][kk], bw[kk][2], acc2[bs][2]);
        acc2[bs][3] = MFMA16(aT[bs][kk], bw[kk][3], acc2[bs][3]);
      }
    unsigned short* H1i = H1T + (size_t)i * 33554432u;
    float svr[4] = {0.f, 0.f, 0.f, 0.f}, sqr[4] = {0.f, 0.f, 0.f, 0.f};
#pragma unroll
    for (int bs = 0; bs < 2; ++bs) {
      int bcur = bs == 0 ? b0 : b1v;
#pragma unroll
      for (int fd = 0; fd < 4; ++fd) {
        int f = fd * 16 + (lane & 15);
        float bia = b1[i * 64 + f];
        float x0 = fmaxf(acc2[bs][fd][0] + bia, 0.f);
        float x1 = fmaxf(acc2[bs][fd][1] + bia, 0.f);
        float x2 = fmaxf(acc2[bs][fd][2] + bia, 0.f);
        float x3 = fmaxf(acc2[bs][fd][3] + bia, 0.f);
        svr[0] += x0; svr[1] += x1; svr[2] += x2; svr[3] += x3;
        sqr[0] += x0 * x0; sqr[1] += x1 * x1; sqr[2] += x2 * x2; sqr[3] += x3 * x3;
        ushort4 p;
        p.x = f2bf(x0); p.y = f2bf(x1); p.z = f2bf(x2); p.w = f2bf(x3);
        *(ushort4*)&H1i[((size_t)bcur * NH + f) * NN + n0 + wid * 16 + (lane >> 4) * 4] = p;
      }
    }
#pragma unroll
    for (int rr = 0; rr < 4; ++rr) {
      float sv = svr[rr], qv = sqr[rr];
      sv += __shfl_xor(sv, 1); sv += __shfl_xor(sv, 2); sv += __shfl_xor(sv, 4); sv += __shfl_xor(sv, 8);
      qv += __shfl_xor(qv, 1); qv += __shfl_xor(qv, 2); qv += __shfl_xor(qv, 4); qv += __shfl_xor(qv, 8);
      if ((lane & 15) == 0) {
        int n = n0 + wid * 16 + (lane >> 4) * 4 + rr;
        atomicAdd(&SS1[i * 512 + n], sv);
        atomicAdd(&SQ1[i * 512 + n], qv);
      }
    }
  }
}

// ---------------- adjB_all: all 3 iterations; BN1 finalize inline ----------------
__global__ __launch_bounds__(256)
void k_adjb_all(const unsigned short* __restrict__ adjbf,
                const float* __restrict__ SS1, const float* __restrict__ SQ1,
                const float* __restrict__ g1, const float* __restrict__ be1,
                unsigned short* __restrict__ ADJB3, float* __restrict__ RC3,
                float* __restrict__ A1, float* __restrict__ C1) {
  __shared__ float red[256];
  int blk = blockIdx.x;                        // 1536 = 3*512
  int i = blk >> 9, n = blk & 511, t = threadIdx.x;
  const float* Ssum = SS1 + i * 512;
  const float* Ssq  = SQ1 + i * 512;
  const float* g    = g1 + i * 512;
  const float* be   = be1 + i * 512;
  unsigned short* adjB = ADJB3 + (size_t)i * 262144;
  float acc = 0.f;
#pragma unroll
  for (int hh = 0; hh < 2; ++hh) {
    int m = t + hh * 256;
    float mean = Ssum[m] * (1.f / 65536.f);
    float var  = Ssq[m] * (1.f / 65536.f) - mean * mean;
    float a = g[m] * rsqrtf(var + 1e-5f);
    float c = be[m] - mean * a;
    if (n == 0) { A1[i * 512 + m] = a; C1[i * 512 + m] = c; }
    float av = bf2f(adjbf[n * NN + m]);
    adjB[n * NN + m] = f2bf(av * a);
    acc += av * c;
  }
  red[t] = acc; __syncthreads();
  for (int s = 128; s > 0; s >>= 1) { if (t < s) red[t] += red[t + s]; __syncthreads(); }
  if (t == 0) RC3[i * 512 + n] = red[0];
}

// ---------------- minrow_all: all 3 iterations in one launch ----------------
__global__ __launch_bounds__(256)
void k_minrow_all(const unsigned short* __restrict__ H2T0,
                  const unsigned short* __restrict__ H2T1,
                  const unsigned short* __restrict__ H2T2,
                  const float* __restrict__ SS2, const float* __restrict__ SQ2,
                  const float* __restrict__ g2, const float* __restrict__ be2,
                  const float* __restrict__ SKIP, float* __restrict__ outs) {
  int blk = blockIdx.x;                        // 49152 = 3*16384
  int i = blk >> 14, rb = blk & 16383;
  const unsigned short* Ht = (i == 0) ? H2T0 : (i == 1) ? H2T1 : H2T2;
  const float* Ssum = SS2 + i * 512;
  const float* Ssq  = SQ2 + i * 512;
  const float* g    = g2 + i * 512;
  const float* be   = be2 + i * 512;
  const float* skip_i = SKIP + i * 65536;
  int t = threadIdx.x, lane = t & 63, wid = t >> 6;
  int row = rb * 4 + wid;                      // b*64 + d
  int b = row >> 6, d = row & 63;
  s16x8 hv = *(const s16x8*)(Ht + (size_t)row * NN + lane * 8);
  float m = 1e30f;
#pragma unroll
  for (int e = 0; e < 8; ++e) {
    int mm = lane * 8 + e;
    float mean = Ssum[mm] * (1.f / 65536.f);
    float var  = Ssq[mm] * (1.f / 65536.f) - mean * mean;
    float a = g[mm] * rsqrtf(var + 1e-5f);
    float c = be[mm] - mean * a;
    m = fminf(m, a * bf2f((unsigned short)hv[e]) + c);
  }
#pragma unroll
  for (int off = 1; off < 64; off <<= 1) m = fminf(m, __shfl_xor(m, off));
  if (lane == 0) outs[(size_t)b * 192 + i * 64 + d] = m + skip_i[row];
}

// ---------------- layer2_all: 3 iterations x 2-batch x 4 ntiles in one launch ----------------
__global__ __launch_bounds__(512)
void k_layer2(const unsigned short* __restrict__ H1T, const unsigned short* __restrict__ ADJB3,
              const float* __restrict__ RC3, const unsigned short* __restrict__ W2t,
              const float* __restrict__ b2,
              unsigned short* __restrict__ H2T0, unsigned short* __restrict__ H2T1,
              unsigned short* __restrict__ H2T2,
              float* __restrict__ SS2, float* __restrict__ SQ2,
              const float* __restrict__ A1, const float* __restrict__ C1,
              float* __restrict__ SKIP) {
  __shared__ unsigned short Ab[2][2][4096];    // [b][dbuf]
  __shared__ unsigned short Bb[2][8192];       // reused as Gt0/Gt1
  __shared__ float acs[512], ccs[512];
  int h = blockIdx.x;
  int blk = (h & 7) * 768 + (h >> 3);          // bijective (6144 % 8 == 0)
  int i = blk / 2048;
  int r2 = blk - i * 2048;
  int bp = r2 >> 2, n0 = (r2 & 3) << 7;
  int b0 = bp * 2, b1v = bp * 2 + 1;
  const unsigned short* H1t_i = H1T + (size_t)i * 33554432u;
  const unsigned short* adjB  = ADJB3 + (size_t)i * 262144;
  const unsigned short* W2t_i = W2t + i * 4096;
  const float* rc  = RC3 + i * 512;
  const float* b2_i = b2 + i * 64;
  const float* A1v = A1 + i * 512;
  const float* C1v = C1 + i * 512;
  float* Ssum2 = SS2 + i * 512;
  float* Ssq2  = SQ2 + i * 512;
  float* skip_i = SKIP + i * 65536;
  unsigned short* H2t = (i == 0) ? H2T0 : (i == 1) ? H2T1 : H2T2;

  int t = threadIdx.x, lane = t & 63, wid = t >> 6;
  int wf = wid & 1, wn = wid >> 1;
  bool do_min = (n0 == 0);
  int arow = wid * 8 + (lane >> 3);            // 0..63 (= f)
  int swz = ((lane & 7) ^ (arow & 7)) << 3;
  const unsigned short* aS0 = H1t_i + ((size_t)b0  * NH + arow) * NN + swz;
  const unsigned short* aS1 = H1t_i + ((size_t)b1v * NH + arow) * NN + swz;
  const unsigned short* bS0 = adjB + (size_t)(n0 + arow) * NN + swz;
  const unsigned short* bS1 = adjB + (size_t)(n0 + 64 + arow) * NN + swz;
  acs[t] = A1v[t]; ccs[t] = C1v[t];
  float rcv[2];
  rcv[0] = rc[n0 + wn * 32 + (lane & 15)];
  rcv[1] = rc[n0 + wn * 32 + 16 + (lane & 15)];

  GLOAD16(aS0, &Ab[0][0][wid * 512]);
  GLOAD16(aS1, &Ab[1][0][wid * 512]);
  GLOAD16(bS0, &Bb[0][wid * 512]);
  GLOAD16(bS1, &Bb[0][4096 + wid * 512]);
  __syncthreads();

  float mn0 = 1e30f, mn1 = 1e30f;
  f32x4 acc[2][2][2] = {};
  for (int kt = 0; kt < 8; ++kt) {
    int cur = kt & 1;
    if (kt < 7) {
      int off = (kt + 1) * 64;
      GLOAD16(aS0 + off, &Ab[0][cur ^ 1][wid * 512]);
      GLOAD16(aS1 + off, &Ab[1][cur ^ 1][wid * 512]);
      GLOAD16(bS0 + off, &Bb[cur ^ 1][wid * 512]);
      GLOAD16(bS1 + off, &Bb[cur ^ 1][4096 + wid * 512]);
    }
    if (do_min) {
      int s2 = ((lane & 7) ^ (arow & 7)) << 3;
      s16x8 av0 = *(const s16x8*)&Ab[0][cur][arow * 64 + s2];
      s16x8 av1 = *(const s16x8*)&Ab[1][cur][arow * 64 + s2];
      int m0 = kt * 64 + ((lane & 7) << 3);
#pragma unroll
      for (int e = 0; e < 8; ++e) {
        mn0 = fminf(mn0, acs[m0 + e] * bf2f((unsigned short)av0[e]) + ccs[m0 + e]);
        mn1 = fminf(mn1, acs[m0 + e] * bf2f((unsigned short)av1[e]) + ccs[m0 + e]);
      }
    }
    const unsigned short* B = Bb[cur];
#pragma unroll
    for (int kk = 0; kk < 2; ++kk) {
      int ks = (lane >> 4) + kk * 4;
      int ra0 = wf * 32 + (lane & 15), ra1 = ra0 + 16;
      int rb0 = wn * 32 + (lane & 15), rb1 = rb0 + 16;
      s16x8 bf0 = *(const s16x8*)&B[rb0 * 64 + ((ks ^ (rb0 & 7)) << 3)];
      s16x8 bf1 = *(const s16x8*)&B[rb1 * 64 + ((ks ^ (rb1 & 7)) << 3)];
#pragma unroll
      for (int bs = 0; bs < 2; ++bs) {
        const unsigned short* A = Ab[bs][cur];
        s16x8 a0 = *(const s16x8*)&A[ra0 * 64 + ((ks ^ (ra0 & 7)) << 3)];
        s16x8 a1 = *(const s16x8*)&A[ra1 * 64 + ((ks ^ (ra1 & 7)) << 3)];
        acc[bs][0][0] = MFMA16(a0, bf0, acc[bs][0][0]);
        acc[bs][1][0] = MFMA16(a1, bf0, acc[bs][1][0]);
        acc[bs][0][1] = MFMA16(a0, bf1, acc[bs][0][1]);
        acc[bs][1][1] = MFMA16(a1, bf1, acc[bs][1][1]);
      }
    }
    __syncthreads();
  }
  if (do_min) {
    mn0 = fminf(mn0, __shfl_xor(mn0, 1)); mn1 = fminf(mn1, __shfl_xor(mn1, 1));
    mn0 = fminf(mn0, __shfl_xor(mn0, 2)); mn1 = fminf(mn1, __shfl_xor(mn1, 2));
    mn0 = fminf(mn0, __shfl_xor(mn0, 4)); mn1 = fminf(mn1, __shfl_xor(mn1, 4));
    if ((lane & 7) == 0) {
      skip_i[b0 * 64 + arow] = mn0;
      skip_i[b1v * 64 + arow] = mn1;
    }
  }
  // Gt_b[n][f] = D1[f][n] + rc[n]
#pragma unroll
  for (int bs = 0; bs < 2; ++bs) {
    unsigned short* Gt = Bb[bs];
#pragma unroll
    for (int fi = 0; fi < 2; ++fi)
#pragma unroll
      for (int fj = 0; fj < 2; ++fj) {
        int n  = wn * 32 + fj * 16 + (lane & 15);
        int f0 = wf * 32 + fi * 16 + (lane >> 4) * 4;
        ushort4 p;
        p.x = f2bf(acc[bs][fi][fj][0] + rcv[fj]); p.y = f2bf(acc[bs][fi][fj][1] + rcv[fj]);
        p.z = f2bf(acc[bs][fi][fj][2] + rcv[fj]); p.w = f2bf(acc[bs][fi][fj][3] + rcv[fj]);
        *(ushort4*)&Gt[n * 64 + (((f0 >> 3) ^ (n & 7)) << 3) + (f0 & 7)] = p;
      }
  }
  __syncthreads();
  // stage2: D2[n][d] = Gt_b @ W2t (W2 frags shared across b)
  s16x8 w2f[2][4];
  float bb[4];
#pragma unroll
  for (int kk = 0; kk < 2; ++kk)
#pragma unroll
    for (int fd = 0; fd < 4; ++fd)
      w2f[kk][fd] = *(const s16x8*)&W2t_i[(fd * 16 + (lane & 15)) * 64 + kk * 32 + (lane >> 4) * 8];
#pragma unroll
  for (int fd = 0; fd < 4; ++fd) bb[fd] = b2_i[fd * 16 + (lane & 15)];

  int nrow = wid * 16 + (lane & 15);
  f32x4 acc2[2][4] = {};
#pragma unroll
  for (int bs = 0; bs < 2; ++bs)
#pragma unroll
    for (int kk = 0; kk < 2; ++kk) {
      int ks = (lane >> 4) + kk * 4;
      s16x8 a = *(const s16x8*)&Bb[bs][nrow * 64 + ((ks ^ (nrow & 7)) << 3)];
      acc2[bs][0] = MFMA16(a, w2f[kk][0], acc2[bs][0]);
      acc2[bs][1] = MFMA16(a, w2f[kk][1], acc2[bs][1]);
      acc2[bs][2] = MFMA16(a, w2f[kk][2], acc2[bs][2]);
      acc2[bs][3] = MFMA16(a, w2f[kk][3], acc2[bs][3]);
    }
  float svr[4] = {0.f, 0.f, 0.f, 0.f}, sqr[4] = {0.f, 0.f, 0.f, 0.f};
#pragma unroll
  for (int bs = 0; bs < 2; ++bs) {
    int bcur = bs == 0 ? b0 : b1v;
#pragma unroll
    for (int fd = 0; fd < 4; ++fd) {
      int d  = fd * 16 + (lane & 15);
      int nw = n0 + wid * 16 + (lane >> 4) * 4;
      float x0 = fmaxf(acc2[bs][fd][0] + bb[fd], 0.f);
      float x1 = fmaxf(acc2[bs][fd][1] + bb[fd], 0.f);
      float x2 = fmaxf(acc2[bs][fd][2] + bb[fd], 0.f);
      float x3 = fmaxf(acc2[bs][fd][3] + bb[fd], 0.f);
      svr[0] += x0; svr[1] += x1; svr[2] += x2; svr[3] += x3;
      sqr[0] += x0 * x0; sqr[1] += x1 * x1; sqr[2] += x2 * x2; sqr[3] += x3 * x3;
      ushort4 p;
      p.x = f2bf(x0); p.y = f2bf(x1); p.z = f2bf(x2); p.w = f2bf(x3);
      *(ushort4*)&H2t[((size_t)bcur * NH + d) * NN + nw] = p;
    }
  }
#pragma unroll
  for (int rr = 0; rr < 4; ++rr) {
    float sv = svr[rr], qv = sqr[rr];
    sv += __shfl_xor(sv, 1); sv += __shfl_xor(sv, 2); sv += __shfl_xor(sv, 4); sv += __shfl_xor(sv, 8);
    qv += __shfl_xor(qv, 1); qv += __shfl_xor(qv, 2); qv += __shfl_xor(qv, 4); qv += __shfl_xor(qv, 8);
    if ((lane & 15) == 0) {
      int n = n0 + wid * 16 + (lane >> 4) * 4 + rr;
      atomicAdd(&Ssum2[n], sv);
      atomicAdd(&Ssq2[n], qv);
    }
  }
}

// ---------------- final FC ----------------
__global__ __launch_bounds__(256)
void k_fc(const float* __restrict__ outs, const float* __restrict__ Wfc,
          const float* __restrict__ bfc, float* __restrict__ out) {
  int t = threadIdx.x;
  int b = blockIdx.x * 8 + (t >> 5), o = t & 31;
  float acc = bfc[o];
  const float* orow = outs + (size_t)b * 192;
  for (int j = 0; j < 192; ++j) acc += orow[j] * Wfc[j * 32 + o];
  out[b * 32 + o] = acc;
}

extern "C" void kernel_launch(void* const* d_in, const int* in_sizes, int n_in,
                              void* d_out, int out_size, void* d_ws, size_t ws_size,
                              hipStream_t stream) {
  const float* X   = (const float*)d_in[0];
  const float* adj = (const float*)d_in[1];
  const float* W1  = (const float*)d_in[2];
  const float* b1  = (const float*)d_in[3];
  const float* g1  = (const float*)d_in[4];
  const float* be1 = (const float*)d_in[5];
  const float* W2  = (const float*)d_in[6];
  const float* b2  = (const float*)d_in[7];
  const float* g2  = (const float*)d_in[8];
  const float* be2 = (const float*)d_in[9];
  const float* Wfc = (const float*)d_in[10];
  const float* bfc = (const float*)d_in[11];
  float* out = (float*)d_out;

  char* ws = (char*)d_ws;
  size_t off = 0;
  auto alloc = [&](size_t bytes) {
    char* p = ws + off; off += (bytes + 255) & ~(size_t)255; return p;
  };
  unsigned short* ADJBF = (unsigned short*)alloc(512 * 512 * 2);
  unsigned short* ADJB3 = (unsigned short*)alloc((size_t)3 * 512 * 512 * 2);
  unsigned short* W1T   = (unsigned short*)alloc(3 * 4096 * 2);
  unsigned short* W2T   = (unsigned short*)alloc(3 * 4096 * 2);
  float* SS1 = (float*)alloc(3 * 512 * 4);   // contiguous 4x6144B for one memset
  float* SQ1 = (float*)alloc(3 * 512 * 4);
  float* SS2 = (float*)alloc(3 * 512 * 4);
  float* SQ2 = (float*)alloc(3 * 512 * 4);
  float* A1  = (float*)alloc(3 * 512 * 4);
  float* C1  = (float*)alloc(3 * 512 * 4);
  float* RC3 = (float*)alloc(3 * 512 * 4);
  float* SKIP = (float*)alloc(3 * 1024 * 64 * 4);
  float* OUTS = (float*)alloc(1024 * 192 * 4);
  unsigned short* XT   = (unsigned short*)alloc((size_t)1024 * 64 * 512 * 2);  // reused as H2T0
  unsigned short* H1T  = (unsigned short*)alloc((size_t)3 * 1024 * 64 * 512 * 2);
  unsigned short* H2T1 = (unsigned short*)alloc((size_t)1024 * 64 * 512 * 2);
  unsigned short* H2T2 = (unsigned short*)alloc((size_t)1024 * 64 * 512 * 2);
  unsigned short* H2T0 = XT;   // Xt dead after k_gnn1

  hipMemsetAsync(SS1, 0, 4 * 3 * 512 * 4, stream);

  k_prep<<<9264, 256, 0, stream>>>(X, adj, W1, W2, XT, ADJBF, W1T, W2T);
  k_gnn1<<<2048, 512, 0, stream>>>(XT, ADJBF, W1T, b1, H1T, SS1, SQ1);
  k_adjb_all<<<1536, 256, 0, stream>>>(ADJBF, SS1, SQ1, g1, be1, ADJB3, RC3, A1, C1);
  k_layer2<<<6144, 512, 0, stream>>>(H1T, ADJB3, RC3, W2T, b2,
                                     H2T0, H2T1, H2T2, SS2, SQ2, A1, C1, SKIP);
  k_minrow_all<<<49152, 256, 0, stream>>>(H2T0, H2T1, H2T2, SS2, SQ2, g2, be2,
                                          SKIP, OUTS);
  k_fc<<<128, 256, 0, stream>>>(OUTS, Wfc, bfc, out);
}